// Round 1
// baseline (488.827 us; speedup 1.0000x reference)
//
#include <hip/hip_runtime.h>

#define N_ENTITIES 500000
#define N_RELS 1000
#define EMB_DIM 128
#define N_TRIPLES 1000000

#define ROWS_PER_THREAD 4
#define ROW_STRIDE (N_ENTITIES / ROWS_PER_THREAD)  // 125000 exact

typedef float floatx4 __attribute__((ext_vector_type(4)));
typedef unsigned long long u64;

// pack[v] encodes the winning triple for entity v, pre-joined with its
// indices so apply never touches r_idx/t_idx:
//   key = (e+1)<<29 | r<<19 | t      (t < 2^19, r < 2^10, e+1 < 2^20)
//   0   = no winner
// max over keys == max over e (e in high bits)  => last-write-wins,
// order-independent => deterministic under graph replay.

__global__ void init_pack_kernel(u64* __restrict__ pack) {
    int i = blockIdx.x * blockDim.x + threadIdx.x;
    if (i < N_ENTITIES) pack[i] = 0ull;
}

__global__ void find_winner_kernel(const int4* __restrict__ h4,
                                   const int4* __restrict__ r4,
                                   const int4* __restrict__ t4,
                                   u64* __restrict__ pack) {
    int q = blockIdx.x * blockDim.x + threadIdx.x;  // quad of triples
    if (q >= N_TRIPLES / 4) return;
    int4 h = h4[q];
    int4 r = r4[q];
    int4 t = t4[q];
    u64 e1 = (u64)(4 * q + 1);
    atomicMax(&pack[h.x], (e1      << 29) | ((u64)r.x << 19) | (u64)t.x);
    atomicMax(&pack[h.y], ((e1 + 1) << 29) | ((u64)r.y << 19) | (u64)t.y);
    atomicMax(&pack[h.z], ((e1 + 2) << 29) | ((u64)r.z << 19) | (u64)t.z);
    atomicMax(&pack[h.w], ((e1 + 3) << 29) | ((u64)r.w << 19) | (u64)t.w);
}

// One row = 128 floats = 32 lanes x float4. Each thread owns 4 rows spaced
// ROW_STRIDE apart: 4 independent load chains per thread (4x MLP), with the
// chain shortened to pack(streamed) -> {rv,tv} gathers. Out-stores are
// nontemporal so the 244 MB memory stream stays resident in L3 and random
// t-row gathers mostly hit it.
__global__ void apply_kernel(const float* __restrict__ memory,
                             const float* __restrict__ rel_table,
                             const u64* __restrict__ pack,
                             float* __restrict__ out) {
    int tid  = blockIdx.x * blockDim.x + threadIdx.x;
    int row0 = tid >> 5;
    int lane = tid & 31;
    if (row0 >= ROW_STRIDE) return;

    int rows[ROWS_PER_THREAD];
    u64 k[ROWS_PER_THREAD];
#pragma unroll
    for (int i = 0; i < ROWS_PER_THREAD; ++i) {
        rows[i] = row0 + i * ROW_STRIDE;
        k[i] = pack[rows[i]];                       // streamed 8B, broadcast
    }

    floatx4 h[ROWS_PER_THREAD];
#pragma unroll
    for (int i = 0; i < ROWS_PER_THREAD; ++i)
        h[i] = ((const floatx4*)(memory + (size_t)rows[i] * EMB_DIM))[lane];

    floatx4 rv[ROWS_PER_THREAD], tv[ROWS_PER_THREAD];
#pragma unroll
    for (int i = 0; i < ROWS_PER_THREAD; ++i) {
        int t = (int)(k[i] & 0x7FFFF);              // row 0 when no winner
        int r = (int)((k[i] >> 19) & 0x3FF);        // rel 0 when no winner
        rv[i] = ((const floatx4*)(rel_table + (size_t)r * EMB_DIM))[lane];
        tv[i] = ((const floatx4*)(memory    + (size_t)t * EMB_DIM))[lane];
    }

#pragma unroll
    for (int i = 0; i < ROWS_PER_THREAD; ++i) {
        // Keep the exact arithmetic of the verified kernel for winner rows;
        // exact h passthrough for non-winner rows (select, not scale-by-0).
        floatx4 upd = 0.9f * h[i] + 0.1f * (h[i] + rv[i] - tv[i]);
        floatx4 val = (k[i] != 0ull) ? upd : h[i];
        floatx4* orow = (floatx4*)(out + (size_t)rows[i] * EMB_DIM) + lane;
        __builtin_nontemporal_store(val, orow);
    }
}

extern "C" void kernel_launch(void* const* d_in, const int* in_sizes, int n_in,
                              void* d_out, int out_size, void* d_ws, size_t ws_size,
                              hipStream_t stream) {
    const float* memory    = (const float*)d_in[0];
    const float* rel_table = (const float*)d_in[1];
    const int*   h_idx     = (const int*)d_in[2];
    const int*   r_idx     = (const int*)d_in[3];
    const int*   t_idx     = (const int*)d_in[4];
    float*       out       = (float*)d_out;

    u64* pack = (u64*)d_ws;  // N_ENTITIES u64 = 4 MB

    {
        int threads = 256;
        int blocks = (N_ENTITIES + threads - 1) / threads;
        init_pack_kernel<<<blocks, threads, 0, stream>>>(pack);
    }
    {
        int threads = 256;
        int quads = N_TRIPLES / 4;
        int blocks = (quads + threads - 1) / threads;
        find_winner_kernel<<<blocks, threads, 0, stream>>>(
            (const int4*)h_idx, (const int4*)r_idx, (const int4*)t_idx, pack);
    }
    {
        int threads = 256;
        long long total = (long long)ROW_STRIDE * 32;
        int blocks = (int)((total + threads - 1) / threads);
        apply_kernel<<<blocks, threads, 0, stream>>>(memory, rel_table, pack, out);
    }
}

// Round 2
// 483.943 us; speedup vs baseline: 1.0101x; 1.0101x over previous
//
#include <hip/hip_runtime.h>

#define N_ENTITIES 500000
#define N_RELS 1000
#define EMB_DIM 128
#define N_TRIPLES 1000000

// Each 256-thread block owns a contiguous 32-row tile (32 x 512 B = 16 KB).
// Step i covers 8 consecutive rows; each wave's loads/stores are adjacent
// 1 KB bursts. 500000 / 32 = 15625 blocks exactly.
#define STEPS 4
#define ROWS_PER_STEP 8
#define BLOCK_ROWS (STEPS * ROWS_PER_STEP)

typedef float floatx4 __attribute__((ext_vector_type(4)));
typedef unsigned long long u64;

// pack[v] encodes the winning triple for entity v, pre-joined with its
// indices so apply never touches r_idx/t_idx:
//   key = (e+1)<<29 | r<<19 | t      (t < 2^19, r < 2^10, e+1 < 2^20)
//   0   = no winner
// max over keys == max over e (e in high bits)  => last-write-wins,
// order-independent => deterministic under graph replay.

__global__ void init_pack_kernel(u64* __restrict__ pack) {
    int i = blockIdx.x * blockDim.x + threadIdx.x;
    if (i < N_ENTITIES) pack[i] = 0ull;
}

__global__ void find_winner_kernel(const int4* __restrict__ h4,
                                   const int4* __restrict__ r4,
                                   const int4* __restrict__ t4,
                                   u64* __restrict__ pack) {
    int q = blockIdx.x * blockDim.x + threadIdx.x;  // quad of triples
    if (q >= N_TRIPLES / 4) return;
    int4 h = h4[q];
    int4 r = r4[q];
    int4 t = t4[q];
    u64 e1 = (u64)(4 * q + 1);
    atomicMax(&pack[h.x], (e1      << 29) | ((u64)r.x << 19) | (u64)t.x);
    atomicMax(&pack[h.y], ((e1 + 1) << 29) | ((u64)r.y << 19) | (u64)t.y);
    atomicMax(&pack[h.z], ((e1 + 2) << 29) | ((u64)r.z << 19) | (u64)t.z);
    atomicMax(&pack[h.w], ((e1 + 3) << 29) | ((u64)r.w << 19) | (u64)t.w);
}

// One row = 128 floats = 32 lanes x float4. Each thread handles 4 rows within
// its block's contiguous 32-row tile (NOT strided across the table: round-1's
// 64MB-apart streams cost ~7% DRAM efficiency). Chain per row is
// pack(streamed) -> {rv,tv} gathers; t-gathers hit L3 because the memory
// stream passes through it and out-stores are nontemporal (no L3 eviction).
__global__ void apply_kernel(const float* __restrict__ memory,
                             const float* __restrict__ rel_table,
                             const u64* __restrict__ pack,
                             float* __restrict__ out) {
    int lane = threadIdx.x & 31;
    int hr   = threadIdx.x >> 5;                    // 0..7: half-wave index
    int base = blockIdx.x * BLOCK_ROWS;

    int rows[STEPS];
    u64 k[STEPS];
#pragma unroll
    for (int i = 0; i < STEPS; ++i) {
        rows[i] = base + i * ROWS_PER_STEP + hr;    // contiguous per step
        k[i] = pack[rows[i]];                       // broadcast 8B per half-wave
    }

    floatx4 h[STEPS];
#pragma unroll
    for (int i = 0; i < STEPS; ++i)
        h[i] = ((const floatx4*)(memory + (size_t)rows[i] * EMB_DIM))[lane];

    floatx4 rv[STEPS], tv[STEPS];
#pragma unroll
    for (int i = 0; i < STEPS; ++i) {
        int t = (int)(k[i] & 0x7FFFF);              // row 0 when no winner
        int r = (int)((k[i] >> 19) & 0x3FF);        // rel 0 when no winner
        rv[i] = ((const floatx4*)(rel_table + (size_t)r * EMB_DIM))[lane];
        tv[i] = ((const floatx4*)(memory    + (size_t)t * EMB_DIM))[lane];
    }

#pragma unroll
    for (int i = 0; i < STEPS; ++i) {
        // Exact arithmetic of the verified kernel for winner rows; exact h
        // passthrough for non-winner rows (select, not scale-by-0).
        floatx4 upd = 0.9f * h[i] + 0.1f * (h[i] + rv[i] - tv[i]);
        floatx4 val = (k[i] != 0ull) ? upd : h[i];
        floatx4* orow = (floatx4*)(out + (size_t)rows[i] * EMB_DIM) + lane;
        __builtin_nontemporal_store(val, orow);
    }
}

extern "C" void kernel_launch(void* const* d_in, const int* in_sizes, int n_in,
                              void* d_out, int out_size, void* d_ws, size_t ws_size,
                              hipStream_t stream) {
    const float* memory    = (const float*)d_in[0];
    const float* rel_table = (const float*)d_in[1];
    const int*   h_idx     = (const int*)d_in[2];
    const int*   r_idx     = (const int*)d_in[3];
    const int*   t_idx     = (const int*)d_in[4];
    float*       out       = (float*)d_out;

    u64* pack = (u64*)d_ws;  // N_ENTITIES u64 = 4 MB

    {
        int threads = 256;
        int blocks = (N_ENTITIES + threads - 1) / threads;
        init_pack_kernel<<<blocks, threads, 0, stream>>>(pack);
    }
    {
        int threads = 256;
        int quads = N_TRIPLES / 4;
        int blocks = (quads + threads - 1) / threads;
        find_winner_kernel<<<blocks, threads, 0, stream>>>(
            (const int4*)h_idx, (const int4*)r_idx, (const int4*)t_idx, pack);
    }
    {
        int threads = 256;
        int blocks = N_ENTITIES / BLOCK_ROWS;       // 15625 exact
        apply_kernel<<<blocks, threads, 0, stream>>>(memory, rel_table, pack, out);
    }
}